// Round 6
// baseline (5567.709 us; speedup 1.0000x reference)
//
#include <hip/hip_runtime.h>
#include <hip/hip_bf16.h>

typedef __hip_bfloat16 bf16;
typedef __attribute__((ext_vector_type(8))) short short8;
typedef __attribute__((ext_vector_type(4))) float floatx4;
typedef unsigned short ush;

#define HH 128
#define WW 128
#define HW 16384

__device__ __forceinline__ float b2f(bf16 v){ return __bfloat162float(v); }
__device__ __forceinline__ float bfu2f(ush u){
  union{unsigned int i; float f;} c; c.i = ((unsigned int)u)<<16; return c.f;
}
__device__ __forceinline__ ush f2bfu(float f){
  bf16 h = __float2bfloat16(f);
  return *(ush*)&h;
}

// ---------- dtype detector: flag=1.0 if x is bf16, 0.0 if f32
__global__ void detect_dtype(const ush* __restrict__ x, float* __restrict__ flag){
  __shared__ int bad;
  if (threadIdx.x==0) bad = 0;
  __syncthreads();
  for (int j=threadIdx.x; j<4096; j+=256){
    float f = bfu2f(x[j]);
    if (!(fabsf(f) < 1e4f)) atomicOr(&bad, 1);
  }
  __syncthreads();
  if (threadIdx.x==0) flag[0] = bad ? 0.f : 1.f;
}

// ---------- input convert: src (bf16 or f32 per flag) -> f32
__global__ void convert_in(const void* __restrict__ src, float* __restrict__ dst, int n,
                           const float* __restrict__ flag){
  int i = blockIdx.x*256 + threadIdx.x;
  if (i >= n) return;
  float v = (flag[0] > 0.5f) ? b2f(((const bf16*)src)[i]) : ((const float*)src)[i];
  dst[i] = v;
}

// ---------- weight transpose: src f32 [Co][CiK] -> dst f32 [CiK][Co]
__global__ void transpose_w(const float* __restrict__ src, float* __restrict__ dst, int Co, int CiK){
  int tid = blockIdx.x*256 + threadIdx.x;
  if (tid >= Co*CiK) return;
  int co = tid / CiK, r = tid - co*CiK;
  dst[(long)r*Co + co] = src[tid];
}

// ---------- weight pack: f32 [Cout][Cin][3][3] -> bf16 [nOcB][64][9][64] (K-half kh)
__global__ void pack_w(const float* __restrict__ src, ush* __restrict__ dst,
                       int Cout, int Cin, int kh, int nOcB){
  int idx = blockIdx.x*256 + threadIdx.x;
  int total = nOcB*36864;
  if (idx >= total) return;
  int ocb = idx / 36864; int r = idx - ocb*36864;
  int oc = r / 576; int r2 = r - oc*576;
  int t = r2 >> 6; int ic = r2 & 63;
  int ocg = ocb*64 + oc, icg = kh*64 + ic;
  float v = (ocg < Cout && icg < Cin) ? src[((long)ocg*Cin + icg)*9 + t] : 0.f;
  dst[idx] = f2bfu(v);
}

// ---------- DCN weight pack: f32 [64 oc][64 ic][9] -> bf16 [8 g][64 oc][96]
__global__ void pack_dcn_w(const float* __restrict__ src, ush* __restrict__ dst){
  int idx = blockIdx.x*256 + threadIdx.x;
  if (idx >= 49152) return;
  int g = idx / 6144; int r = idx - g*6144;
  int oc = r / 96; int k = r - oc*96;
  float v = 0.f;
  if (k < 72){
    int tap = k >> 3, c = k & 7;
    v = src[((long)oc*64 + g*8 + c)*9 + tap];
  }
  dst[idx] = f2bfu(v);
}

// ---------- conv_init: x f32 [20][HW] -> feat NHWC hi/lo bf16 [20][HW][64], relu
__global__ __launch_bounds__(256) void conv_init_kernel(const float* __restrict__ x,
    const float* __restrict__ wT, const float* __restrict__ bias,
    ush* __restrict__ fh, ush* __restrict__ fl){
  int tx = threadIdx.x & 15, ty = threadIdx.x >> 4;
  int gx = blockIdx.x*16+tx, gy = blockIdx.y*16+ty;
  int n = blockIdx.z;
  const float* xp = x + (long)n*HW;
  float v[9];
  #pragma unroll
  for (int dy=0;dy<3;dy++)
    #pragma unroll
    for (int dx=0;dx<3;dx++){
      int yy = gy+dy-1, xx = gx+dx-1;
      bool ok = (yy>=0)&&(yy<HH)&&(xx>=0)&&(xx<WW);
      v[dy*3+dx] = ok ? xp[yy*WW+xx] : 0.f;
    }
  long base = ((long)n*HW + gy*WW + gx)*64;
  #pragma unroll 1
  for (int oc=0; oc<64; oc++){
    float acc = bias[oc];
    #pragma unroll
    for (int k=0;k<9;k++) acc = fmaf(v[k], wT[k*64+oc], acc);
    acc = fmaxf(acc, 0.f);
    ush h = f2bfu(acc);
    fh[base+oc] = h;
    fl[base+oc] = f2bfu(acc - bfu2f(h));
  }
}

// ---------- MFMA implicit-GEMM 3x3 SAME conv (NPL = # activation planes)
template<int NPL, int MINW>
__global__ __launch_bounds__(256, MINW) void conv_mfma(
    const ush* __restrict__ in_hi, const ush* __restrict__ in_lo, long in_ps,
    const ush* __restrict__ wpack,
    const float* __restrict__ bias, int has_bias,
    const ush* __restrict__ add_hi, const ush* __restrict__ add_lo,
    long add_ps, int add_cs,
    ush* __restrict__ out_hi, ush* __restrict__ out_lo,
    long out_ps, int out_cs,
    float* __restrict__ out_pf, int pf_C,
    int Cout, int nOcB, int relu)
{
  __shared__ ush A[NPL*11520];
  __shared__ ush Bb[2*4096];
  int tid = threadIdx.x;
  int z = blockIdx.z; int img = z / nOcB; int ocb = z - img*nOcB;
  int x0 = blockIdx.x*16 - 1, y0 = blockIdx.y*8 - 1;
  // ---- B register prefetch (all 9 taps) issued first
  const ush* wsrc = wpack + (long)ocb*36864;
  uint4 bReg[9][2];
  #pragma unroll
  for (int t=0;t<9;t++){
    #pragma unroll
    for (int it=0;it<2;it++){
      int j = tid + it*256;
      int oc = j>>3, c8 = j&7;
      bReg[t][it] = *(const uint4*)(wsrc + oc*576 + t*64 + c8*8);
    }
  }
  // ---- A staging
  const ush* ih = in_hi + (long)img*in_ps*64;
  const ush* il = in_lo + (long)img*in_ps*64;
  #pragma unroll
  for (int p=0;p<NPL;p++){
    const ush* src = p ? il : ih;
    ush* dstp = A + p*11520;
    for (int j=tid; j<1440; j+=256){
      int pidx = j>>3, c8 = j&7;
      int row = pidx/18, col = pidx - row*18;
      int yy = y0+row, xx = x0+col;
      uint4 v = make_uint4(0u,0u,0u,0u);
      if ((unsigned)yy < 128u && (unsigned)xx < 128u)
        v = *(const uint4*)(src + ((long)(yy*WW+xx))*64 + c8*8);
      *(uint4*)(dstp + pidx*64 + ((c8 ^ (pidx&7))<<3)) = v;
    }
  }
  auto writeB = [&](int t, int bufsel){
    ush* d = Bb + bufsel*4096;
    #pragma unroll
    for (int it=0; it<2; it++){
      int j = tid + it*256;
      int oc = j>>3, c8 = j&7;
      *(uint4*)(d + oc*64 + ((c8 ^ (oc&7))<<3)) = bReg[t][it];
    }
  };
  writeB(0,0);
  __syncthreads();
  int w = tid>>6, l = tid&63, lx = l&15, lk = l>>4;
  floatx4 acc[2][4];
  #pragma unroll
  for (int mt=0;mt<2;mt++)
    #pragma unroll
    for (int n=0;n<4;n++) acc[mt][n] = (floatx4){0.f,0.f,0.f,0.f};
  #pragma unroll 1
  for (int t=0;t<9;t++){
    if (t<8) writeB(t+1, (t+1)&1);
    int ky = t/3, kx = t - ky*3;
    const ush* Bt = Bb + (t&1)*4096;
    #pragma unroll
    for (int ch=0; ch<2; ch++){
      int jc = ch*4 + lk;
      short8 bf[4];
      #pragma unroll
      for (int n=0;n<4;n++){
        int oc = n*16 + lx;
        bf[n] = *(const short8*)(Bt + oc*64 + ((jc ^ (oc&7))<<3));
      }
      #pragma unroll
      for (int mt=0; mt<2; mt++){
        int pidx = (w*2+mt+ky)*18 + lx + kx;
        #pragma unroll
        for (int p=0;p<NPL;p++){
          short8 af = *(const short8*)(A + p*11520 + pidx*64 + ((jc ^ (pidx&7))<<3));
          #pragma unroll
          for (int n=0;n<4;n++)
            acc[mt][n] = __builtin_amdgcn_mfma_f32_16x16x32_bf16(af, bf[n], acc[mt][n], 0,0,0);
        }
      }
    }
    __syncthreads();
  }
  int ybase = blockIdx.y*8 + w*2;
  int xbase = blockIdx.x*16 + lk*4;
  #pragma unroll
  for (int mt=0;mt<2;mt++){
    int y = ybase + mt;
    #pragma unroll
    for (int n=0;n<4;n++){
      int ocg = ocb*64 + n*16 + lx;
      if (ocg < Cout){
        float bv = has_bias ? bias[ocg] : 0.f;
        #pragma unroll
        for (int r=0;r<4;r++){
          int xg = xbase + r;
          float v = acc[mt][n][r] + bv;
          if (add_hi){
            long ap = ((long)img*add_ps + y*WW + xg)*add_cs + ocg;
            v += bfu2f(add_hi[ap]) + bfu2f(add_lo[ap]);
          }
          if (relu) v = fmaxf(v, 0.f);
          if (out_pf){
            out_pf[((long)img*pf_C + ocg)*HW + y*WW + xg] = v;
          } else {
            long pp = (long)img*out_ps + y*WW + xg;
            ush h = f2bfu(v);
            out_hi[pp*out_cs + ocg] = h;
            if (out_lo) out_lo[pp*out_cs + ocg] = f2bfu(v - bfu2f(h));
          }
        }
      }
    }
  }
}

// ---------- repack NHWC hi/lo -> group-planar f32 [4][8][HW][8]
__global__ __launch_bounds__(256) void repack_gp(const ush* __restrict__ in_h,
    const ush* __restrict__ in_l, long in_ps, float* __restrict__ gp){
  long idx = (long)blockIdx.x*256 + threadIdx.x;
  int img = (int)(idx >> 20);
  int rem = (int)(idx & 1048575);
  int g = rem >> 17;
  int r2 = rem & 131071;
  int pix = r2 >> 3, c = r2 & 7;
  long src = ((long)img*in_ps + pix)*64 + g*8 + c;
  gp[idx] = bfu2f(in_h[src]) + bfu2f(in_l[src]);
}

// ---------- MFMA modulated deformable conv
__global__ __launch_bounds__(256) void dcn_mfma(
    const float* __restrict__ gp,
    const float* __restrict__ om,
    const ush* __restrict__ wpk,
    const float* __restrict__ bias,
    ush* __restrict__ out_hi, ush* __restrict__ out_lo)
{
  __shared__ ush Ah[128*104];
  __shared__ ush Al[128*104];
  __shared__ ush Bt[64*104];
  int tid = threadIdx.x;
  int gy = blockIdx.x, img = blockIdx.y;
  {
    short8 z = {0,0,0,0,0,0,0,0};
    for (int j=tid; j<384; j+=256){
      int px = j/3, c = j - px*3;
      *(short8*)(Ah + px*104 + 72 + c*8) = z;
      *(short8*)(Al + px*104 + 72 + c*8) = z;
    }
  }
  int w = tid>>6, l = tid&63, lx = l&15, lk = l>>4;
  int px_s = tid & 127, hf = tid >> 7;
  const float* omb = om + (long)img*216*HW + gy*WW + px_s;
  floatx4 acc[2][4];
  #pragma unroll
  for (int mt=0;mt<2;mt++)
    #pragma unroll
    for (int n=0;n<4;n++) acc[mt][n] = (floatx4){0.f,0.f,0.f,0.f};

  #pragma unroll 1
  for (int g=0; g<8; g++){
    __syncthreads();
    const ush* wsrc = wpk + g*6144;
    for (int j=tid; j<768; j+=256){
      int oc = j/12, kc = j - oc*12;
      *(short8*)(Bt + oc*104 + kc*8) = *(const short8*)(wsrc + oc*96 + kc*8);
    }
    const float* gpb = gp + ((long)(img*8+g))*HW*8;
    int t0 = hf ? 5 : 0, t1 = hf ? 9 : 5;
    #pragma unroll 1
    for (int t=t0; t<t1; t++){
      int ch = g*9+t;
      float dy = omb[(long)ch*HW];
      float dx = omb[(long)(72+ch)*HW];
      float mv = omb[(long)(144+ch)*HW];
      float m = 1.f/(1.f+__expf(-mv));
      float py = (float)gy + (float)(t/3 - 1) + dy;
      float pxf = (float)px_s + (float)(t%3 - 1) + dx;
      float fy = floorf(py), fx = floorf(pxf);
      int y0 = (int)fy, x0 = (int)fx;
      float wy = py - fy, wx = pxf - fx;
      bool y0v = (y0>=0 && y0<HH), y1v = (y0+1>=0 && y0+1<HH);
      bool x0v = (x0>=0 && x0<WW), x1v = (x0+1>=0 && x0+1<WW);
      float w00 = (1.f-wy)*(1.f-wx)*m * ((y0v&&x0v)?1.f:0.f);
      float w01 = (1.f-wy)*wx*m      * ((y0v&&x1v)?1.f:0.f);
      float w10 = wy*(1.f-wx)*m      * ((y1v&&x0v)?1.f:0.f);
      float w11 = wy*wx*m            * ((y1v&&x1v)?1.f:0.f);
      int y0c = min(max(y0,0),HH-1), y1c = min(max(y0+1,0),HH-1);
      int x0c = min(max(x0,0),WW-1), x1c = min(max(x0+1,0),WW-1);
      const float* p00 = gpb + ((long)(y0c*WW+x0c)<<3);
      const float* p01 = gpb + ((long)(y0c*WW+x1c)<<3);
      const float* p10 = gpb + ((long)(y1c*WW+x0c)<<3);
      const float* p11 = gpb + ((long)(y1c*WW+x1c)<<3);
      float4 a00=*(const float4*)p00, b00=*(const float4*)(p00+4);
      float4 a01=*(const float4*)p01, b01=*(const float4*)(p01+4);
      float4 a10=*(const float4*)p10, b10=*(const float4*)(p10+4);
      float4 a11=*(const float4*)p11, b11=*(const float4*)(p11+4);
      float val[8];
      val[0]=w00*a00.x+w01*a01.x+w10*a10.x+w11*a11.x;
      val[1]=w00*a00.y+w01*a01.y+w10*a10.y+w11*a11.y;
      val[2]=w00*a00.z+w01*a01.z+w10*a10.z+w11*a11.z;
      val[3]=w00*a00.w+w01*a01.w+w10*a10.w+w11*a11.w;
      val[4]=w00*b00.x+w01*b01.x+w10*b10.x+w11*b11.x;
      val[5]=w00*b00.y+w01*b01.y+w10*b10.y+w11*b11.y;
      val[6]=w00*b00.z+w01*b01.z+w10*b10.z+w11*b11.z;
      val[7]=w00*b00.w+w01*b01.w+w10*b10.w+w11*b11.w;
      short8 vh, vl;
      #pragma unroll
      for (int c=0;c<8;c++){
        ush h = f2bfu(val[c]);
        vh[c] = (short)h;
        vl[c] = (short)f2bfu(val[c] - bfu2f(h));
      }
      *(short8*)(Ah + px_s*104 + t*8) = vh;
      *(short8*)(Al + px_s*104 + t*8) = vl;
    }
    __syncthreads();
    #pragma unroll
    for (int ks=0; ks<3; ks++){
      short8 bfg[4];
      #pragma unroll
      for (int n=0;n<4;n++)
        bfg[n] = *(const short8*)(Bt + (n*16+lx)*104 + ks*32 + lk*8);
      #pragma unroll
      for (int mt=0; mt<2; mt++){
        int px = (w*2+mt)*16 + lx;
        short8 ah = *(const short8*)(Ah + px*104 + ks*32 + lk*8);
        short8 al = *(const short8*)(Al + px*104 + ks*32 + lk*8);
        #pragma unroll
        for (int n=0;n<4;n++){
          acc[mt][n] = __builtin_amdgcn_mfma_f32_16x16x32_bf16(ah, bfg[n], acc[mt][n], 0,0,0);
          acc[mt][n] = __builtin_amdgcn_mfma_f32_16x16x32_bf16(al, bfg[n], acc[mt][n], 0,0,0);
        }
      }
    }
  }
  long base = ((long)img*HW + gy*WW)*64;
  #pragma unroll
  for (int mt=0;mt<2;mt++){
    #pragma unroll
    for (int n=0;n<4;n++){
      int oc = n*16 + lx;
      float bv = bias[oc];
      #pragma unroll
      for (int r=0;r<4;r++){
        int pxl = (w*2+mt)*16 + lk*4 + r;
        float v = acc[mt][n][r] + bv;
        ush h = f2bfu(v);
        out_hi[base + (long)pxl*64 + oc] = h;
        out_lo[base + (long)pxl*64 + oc] = f2bfu(v - bfu2f(h));
      }
    }
  }
}

// ---------- reconstruction conv: fea NHWC hi/lo -> d_out slot ni
__global__ __launch_bounds__(256) void rec_kernel(
    const ush* __restrict__ fh, const ush* __restrict__ fl,
    const float* __restrict__ wT, const float* __restrict__ bias,
    void* __restrict__ out, int ni, const float* __restrict__ flag){
  int tx = threadIdx.x & 15, ty = threadIdx.x >> 4;
  int gx = blockIdx.x*16+tx, gy = blockIdx.y*16+ty;
  int b = blockIdx.z;
  float acc = bias[0];
  #pragma unroll 1
  for (int t=0;t<9;t++){
    int yy = gy + t/3 - 1, xx = gx + t%3 - 1;
    if (yy<0||yy>=HH||xx<0||xx>=WW) continue;
    long base = ((long)b*HW + yy*WW + xx)*64;
    #pragma unroll
    for (int c8=0;c8<8;c8++){
      short8 h = *(const short8*)(fh + base + c8*8);
      short8 lo = *(const short8*)(fl + base + c8*8);
      #pragma unroll
      for (int cc=0;cc<8;cc++){
        float v = bfu2f((ush)h[cc]) + bfu2f((ush)lo[cc]);
        acc = fmaf(v, wT[(c8*8+cc)*9 + t], acc);
      }
    }
  }
  long idx = ((long)b*5+ni)*HW + gy*WW + gx;
  if (flag[0] > 0.5f) ((bf16*)out)[idx] = __float2bfloat16(acc);
  else                ((float*)out)[idx] = acc;
}

extern "C" void kernel_launch(void* const* d_in, const int* in_sizes, int n_in,
                              void* d_out, int out_size, void* d_ws, size_t ws_size,
                              hipStream_t stream) {
  float* ws = (float*)d_ws;

  size_t off = 16;
  auto alloc = [&](size_t nel){ size_t o = off; off += (nel + 7) & ~(size_t)7; return o; };

  static const int IN_N[17] = {327680, 576, 64, 184320, 320, 184320, 320,
                               73728, 64, 147456, 256, 497664, 864, 147456,
                               256, 576, 1};
  size_t cin[17];
  for (int i=0;i<17;i++) cin[i] = alloc(IN_N[i]);

  size_t wt_init = alloc(640);
  size_t wdcn_pk[4]; for (int s=0;s<4;s++) wdcn_pk[s] = alloc(24576);
  size_t wt_rec = alloc(640);
  size_t pk_res1[5], pk_res2[5];
  for (int i=0;i<5;i++) pk_res1[i] = alloc(18432);
  for (int i=0;i<5;i++) pk_res2[i] = alloc(18432);
  size_t pk_bn[2]; for (int h=0;h<2;h++) pk_bn[h] = alloc(18432);
  size_t pk_off[4]; for (int s=0;s<4;s++) pk_off[s] = alloc(18432);
  size_t pk_com[4]; for (int s=0;s<4;s++) pk_com[s] = alloc(73728);

  size_t feat_h_o = alloc(10485760);
  size_t feat_l_o = alloc(10485760);
  size_t U = alloc(26738688);

  ush* feat_h = (ush*)(ws + feat_h_o);
  ush* feat_l = (ush*)(ws + feat_l_o);
  ush* feaA_h = (ush*)(ws + U);
  ush* feaA_l = (ush*)(ws + U + 2097152);
  ush* feaB_h = (ush*)(ws + U + 4194304);
  ush* feaB_l = (ush*)(ws + U + 6291456);
  ush* obuf_h = (ush*)(ws + U + 8388608);
  ush* obuf_l = (ush*)(ws + U + 10485760);
  float* gpbuf = ws + U + 8388608;       // aliases obuf region when obuf dead
  float* ombuf = ws + U + 12582912;
  ush* hbuf_h = (ush*)(ws + U);
  ush* hbuf_l = (ush*)(ws + U + 10485760);
  ush* part_h = obuf_h;
  ush* part_l = obuf_l;

  float* flag = ws;

  detect_dtype<<<dim3(1), dim3(256), 0, stream>>>((const ush*)d_in[0], flag);
  for (int i=0;i<17;i++){
    int n = IN_N[i];
    convert_in<<<dim3((n+255)/256), dim3(256), 0, stream>>>(d_in[i], ws+cin[i], n, flag);
  }
  const float* b_init = ws+cin[2];
  const float* res_b1 = ws+cin[4];
  const float* res_b2 = ws+cin[6];
  const float* b_bn   = ws+cin[8];
  const float* off_b  = ws+cin[10];
  const float* com_b  = ws+cin[12];
  const float* dcn_b  = ws+cin[14];
  const float* b_rec  = ws+cin[16];

  auto tr = [&](size_t src_o, size_t dst_o, int Co, int CiK){
    int total = Co*CiK;
    transpose_w<<<dim3((total+255)/256), dim3(256), 0, stream>>>(ws+src_o, ws+dst_o, Co, CiK);
  };
  tr(cin[1], wt_init, 64, 9);
  tr(cin[15], wt_rec, 1, 576);
  for (int s=0;s<4;s++)
    pack_dcn_w<<<dim3(192), dim3(256), 0, stream>>>(ws+cin[13]+(size_t)s*36864,
                                                    (ush*)(ws+wdcn_pk[s]));

  auto pack = [&](size_t src_o, size_t dst_o, int Cout, int Cin, int kh, int nOcB){
    int total = nOcB*36864;
    pack_w<<<dim3((total+255)/256), dim3(256), 0, stream>>>(
        ws+src_o, (ush*)(ws+dst_o), Cout, Cin, kh, nOcB);
  };
  for (int i=0;i<5;i++) pack(cin[3]+(size_t)i*36864, pk_res1[i], 64, 64, 0, 1);
  for (int i=0;i<5;i++) pack(cin[5]+(size_t)i*36864, pk_res2[i], 64, 64, 0, 1);
  for (int h=0;h<2;h++) pack(cin[7], pk_bn[h], 64, 128, h, 1);
  for (int s=0;s<4;s++) pack(cin[9]+(size_t)s*36864,  pk_off[s], 64, 64, 0, 1);
  for (int s=0;s<4;s++) pack(cin[11]+(size_t)s*124416, pk_com[s], 216, 64, 0, 4);

  dim3 cblk(256);
  auto conv = [&](const ush* in_h, const ush* in_l, long in_ps, size_t pk,
                  const float* bias, int has_bias,
                  const ush* add_h, const ush* add_l, long add_ps, int add_cs,
                  ush* o_h, ush* o_l, long out_ps, int out_cs,
                  float* o_pf, int pf_C,
                  int Cout, int nOcB, int relu, int N, int nPl){
    if (nPl == 2)
      conv_mfma<2,2><<<dim3(8,16,N*nOcB), cblk, 0, stream>>>(
          in_h, in_l, in_ps, (const ush*)(ws+pk), bias, has_bias,
          add_h, add_l, add_ps, add_cs, o_h, o_l, out_ps, out_cs,
          o_pf, pf_C, Cout, nOcB, relu);
    else
      conv_mfma<1,3><<<dim3(8,16,N*nOcB), cblk, 0, stream>>>(
          in_h, in_l, in_ps, (const ush*)(ws+pk), bias, has_bias,
          add_h, add_l, add_ps, add_cs, o_h, o_l, out_ps, out_cs,
          o_pf, pf_C, Cout, nOcB, relu);
  };

  // ---- feature extraction
  conv_init_kernel<<<dim3(8,8,20), cblk, 0, stream>>>(ws+cin[0], ws+wt_init, b_init,
                                                      feat_h, feat_l);
  for (int i=0;i<5;i++){
    conv(feat_h, feat_l, HW, pk_res1[i], res_b1+(size_t)i*64, 1,
         nullptr, nullptr, 0, 0, hbuf_h, hbuf_l, HW, 64, nullptr, 0, 64, 1, 1, 20, 2);
    conv(hbuf_h, hbuf_l, HW, pk_res2[i], res_b2+(size_t)i*64, 1,
         feat_h, feat_l, HW, 64, feat_h, feat_l, HW, 64, nullptr, 0, 64, 1, 0, 20, 2);
  }
  // ---- per-neighbor alignment
  for (int i=0;i<5;i++){
    conv(feat_h + (size_t)2*HW*64, feat_l + (size_t)2*HW*64, 5L*HW, pk_bn[0], b_bn, 1,
         nullptr, nullptr, 0, 0, part_h, part_l, HW, 64, nullptr, 0, 64, 1, 0, 4, 2);
    conv(feat_h + (size_t)i*HW*64, feat_l + (size_t)i*HW*64, 5L*HW, pk_bn[1], b_bn, 0,
         part_h, part_l, HW, 64, feaA_h, feaA_l, HW, 64, nullptr, 0, 64, 1, 0, 4, 2);
    ush *fa_h = feaA_h, *fa_l = feaA_l, *fb_h = feaB_h, *fb_l = feaB_l;
    for (int s=0;s<4;s++){
      // off conv: hi-only output (feeds offset path; 2^-9 there is negligible)
      conv(fa_h, fa_l, HW, pk_off[s], off_b+(size_t)s*64, 1,
           nullptr, nullptr, 0, 0, obuf_h, nullptr, HW, 64, nullptr, 0, 64, 1, 0, 4, 2);
      // com conv: single-plane input, planar f32 output
      conv(obuf_h, obuf_h, HW, pk_com[s], com_b+(size_t)s*216, 1,
           nullptr, nullptr, 0, 0, nullptr, nullptr, 0, 0, ombuf, 216, 216, 4, 0, 4, 1);
      const ush *xs_h, *xs_l; long xps;
      if (s == 2){ xs_h = feat_h + (size_t)i*HW*64; xs_l = feat_l + (size_t)i*HW*64; xps = 5L*HW; }
      else       { xs_h = fa_h;                     xs_l = fa_l;                     xps = HW; }
      repack_gp<<<dim3(16384), cblk, 0, stream>>>(xs_h, xs_l, xps, gpbuf);
      dcn_mfma<<<dim3(128,4), cblk, 0, stream>>>(gpbuf, ombuf,
          (const ush*)(ws+wdcn_pk[s]), dcn_b+(size_t)s*64, fb_h, fb_l);
      ush* t;
      t = fa_h; fa_h = fb_h; fb_h = t;
      t = fa_l; fa_l = fb_l; fb_l = t;
    }
    rec_kernel<<<dim3(8,8,4), cblk, 0, stream>>>(fa_h, fa_l, ws+wt_rec, b_rec, d_out, i, flag);
  }
}

// Round 7
// 4208.325 us; speedup vs baseline: 1.3230x; 1.3230x over previous
//
#include <hip/hip_runtime.h>
#include <hip/hip_bf16.h>

typedef __hip_bfloat16 bf16;
typedef __attribute__((ext_vector_type(8))) short short8;
typedef __attribute__((ext_vector_type(4))) float floatx4;
typedef unsigned short ush;

#define HH 128
#define WW 128
#define HW 16384

__device__ __forceinline__ float b2f(bf16 v){ return __bfloat162float(v); }
__device__ __forceinline__ float bfu2f(ush u){
  union{unsigned int i; float f;} c; c.i = ((unsigned int)u)<<16; return c.f;
}
__device__ __forceinline__ ush f2bfu(float f){
  bf16 h = __float2bfloat16(f);
  return *(ush*)&h;
}

// ---------- dtype detector: flag=1.0 if x is bf16, 0.0 if f32
__global__ void detect_dtype(const ush* __restrict__ x, float* __restrict__ flag){
  __shared__ int bad;
  if (threadIdx.x==0) bad = 0;
  __syncthreads();
  for (int j=threadIdx.x; j<4096; j+=256){
    float f = bfu2f(x[j]);
    if (!(fabsf(f) < 1e4f)) atomicOr(&bad, 1);
  }
  __syncthreads();
  if (threadIdx.x==0) flag[0] = bad ? 0.f : 1.f;
}

// ---------- input convert: src (bf16 or f32 per flag) -> f32
__global__ void convert_in(const void* __restrict__ src, float* __restrict__ dst, int n,
                           const float* __restrict__ flag){
  int i = blockIdx.x*256 + threadIdx.x;
  if (i >= n) return;
  float v = (flag[0] > 0.5f) ? b2f(((const bf16*)src)[i]) : ((const float*)src)[i];
  dst[i] = v;
}

// ---------- weight transpose: src f32 [Co][CiK] -> dst f32 [CiK][Co]
__global__ void transpose_w(const float* __restrict__ src, float* __restrict__ dst, int Co, int CiK){
  int tid = blockIdx.x*256 + threadIdx.x;
  if (tid >= Co*CiK) return;
  int co = tid / CiK, r = tid - co*CiK;
  dst[(long)r*Co + co] = src[tid];
}

// ---------- weight pack v2: f32 [Cout][Cin][3][3] -> bf16 fragment-order
// per ocb: [j=t*2+ch (18)][lk (4)][n (4)][lx (16)][c (8)]
// oc = n*16+lx, k(within 64) = ch*32 + lk*8 + c, tap = t; K-half kh.
__global__ void pack_w2(const float* __restrict__ src, ush* __restrict__ dst,
                        int Cout, int Cin, int kh, int nOcB){
  int idx = blockIdx.x*256 + threadIdx.x;
  int total = nOcB*36864;
  if (idx >= total) return;
  int ocb = idx / 36864; int r = idx - ocb*36864;
  int c  = r & 7;
  int lx = (r>>3) & 15;
  int n  = (r>>7) & 3;
  int lk = (r>>9) & 3;
  int j  = r>>11;            // 0..17
  int t = j>>1, ch = j&1;
  int oc = n*16+lx;
  int k = ch*32 + lk*8 + c;
  int ocg = ocb*64 + oc, icg = kh*64 + k;
  float v = (ocg < Cout && icg < Cin) ? src[((long)ocg*Cin + icg)*9 + t] : 0.f;
  dst[idx] = f2bfu(v);
}

// ---------- DCN weight pack: f32 [64 oc][64 ic][9] -> bf16 [8 g][64 oc][96]
__global__ void pack_dcn_w(const float* __restrict__ src, ush* __restrict__ dst){
  int idx = blockIdx.x*256 + threadIdx.x;
  if (idx >= 49152) return;
  int g = idx / 6144; int r = idx - g*6144;
  int oc = r / 96; int k = r - oc*96;
  float v = 0.f;
  if (k < 72){
    int tap = k >> 3, c = k & 7;
    v = src[((long)oc*64 + g*8 + c)*9 + tap];
  }
  dst[idx] = f2bfu(v);
}

// ---------- conv_init: x f32 [20][HW] -> feat NHWC hi/lo bf16 [20][HW][64], relu
__global__ __launch_bounds__(256) void conv_init_kernel(const float* __restrict__ x,
    const float* __restrict__ wT, const float* __restrict__ bias,
    ush* __restrict__ fh, ush* __restrict__ fl){
  int tx = threadIdx.x & 15, ty = threadIdx.x >> 4;
  int gx = blockIdx.x*16+tx, gy = blockIdx.y*16+ty;
  int n = blockIdx.z;
  const float* xp = x + (long)n*HW;
  float v[9];
  #pragma unroll
  for (int dy=0;dy<3;dy++)
    #pragma unroll
    for (int dx=0;dx<3;dx++){
      int yy = gy+dy-1, xx = gx+dx-1;
      bool ok = (yy>=0)&&(yy<HH)&&(xx>=0)&&(xx<WW);
      v[dy*3+dx] = ok ? xp[yy*WW+xx] : 0.f;
    }
  long base = ((long)n*HW + gy*WW + gx)*64;
  #pragma unroll 1
  for (int oc=0; oc<64; oc++){
    float acc = bias[oc];
    #pragma unroll
    for (int k=0;k<9;k++) acc = fmaf(v[k], wT[k*64+oc], acc);
    acc = fmaxf(acc, 0.f);
    ush h = f2bfu(acc);
    fh[base+oc] = h;
    fl[base+oc] = f2bfu(acc - bfu2f(h));
  }
}

// ---------- MFMA implicit-GEMM 3x3 SAME conv (NPL planes). B direct from global,
// fragment-packed; no B LDS, no per-tap barriers; 18 unrolled j-steps.
template<int NPL, int MINW>
__global__ __launch_bounds__(256, MINW) void conv_mfma(
    const ush* __restrict__ in_hi, const ush* __restrict__ in_lo, long in_ps,
    const ush* __restrict__ wpack,
    const float* __restrict__ bias, int has_bias,
    const ush* __restrict__ add_hi, const ush* __restrict__ add_lo,
    long add_ps, int add_cs,
    ush* __restrict__ out_hi, ush* __restrict__ out_lo,
    long out_ps, int out_cs,
    float* __restrict__ out_pf, int pf_C,
    int Cout, int nOcB, int relu)
{
  __shared__ ush A[NPL*11520];
  int tid = threadIdx.x;
  int z = blockIdx.z; int img = z / nOcB; int ocb = z - img*nOcB;
  int x0 = blockIdx.x*16 - 1, y0 = blockIdx.y*8 - 1;
  int w = tid>>6, l = tid&63, lx = l&15, lk = l>>4;
  const ush* wfrag = wpack + (long)ocb*36864 + lk*4*128 + lx*8;
  // ---- A staging
  const ush* ih = in_hi + (long)img*in_ps*64;
  const ush* il = in_lo + (long)img*in_ps*64;
  #pragma unroll
  for (int p=0;p<NPL;p++){
    const ush* src = p ? il : ih;
    ush* dstp = A + p*11520;
    for (int j=tid; j<1440; j+=256){
      int pidx = j>>3, c8 = j&7;
      int row = pidx/18, col = pidx - row*18;
      int yy = y0+row, xx = x0+col;
      uint4 v = make_uint4(0u,0u,0u,0u);
      if ((unsigned)yy < 128u && (unsigned)xx < 128u)
        v = *(const uint4*)(src + ((long)(yy*WW+xx))*64 + c8*8);
      *(uint4*)(dstp + pidx*64 + ((c8 ^ (pidx&7))<<3)) = v;
    }
  }
  floatx4 acc[2][4];
  #pragma unroll
  for (int mt=0;mt<2;mt++)
    #pragma unroll
    for (int n=0;n<4;n++) acc[mt][n] = (floatx4){0.f,0.f,0.f,0.f};
  short8 bf[2][4];
  #pragma unroll
  for (int n=0;n<4;n++)
    bf[0][n] = *(const short8*)(wfrag + (0*16 + n)*128);
  __syncthreads();
  #pragma unroll
  for (int j=0;j<18;j++){
    int t = j>>1, ch = j&1;
    if (j<17){
      #pragma unroll
      for (int n=0;n<4;n++)
        bf[(j+1)&1][n] = *(const short8*)(wfrag + ((j+1)*16 + n)*128);
    }
    int ky = t/3, kx = t - ky*3;
    int jc = ch*4 + lk;
    #pragma unroll
    for (int mt=0; mt<2; mt++){
      int pidx = (w*2+mt+ky)*18 + lx + kx;
      #pragma unroll
      for (int p=0;p<NPL;p++){
        short8 af = *(const short8*)(A + p*11520 + pidx*64 + ((jc ^ (pidx&7))<<3));
        #pragma unroll
        for (int n=0;n<4;n++)
          acc[mt][n] = __builtin_amdgcn_mfma_f32_16x16x32_bf16(af, bf[j&1][n], acc[mt][n], 0,0,0);
      }
    }
  }
  int ybase = blockIdx.y*8 + w*2;
  int xbase = blockIdx.x*16 + lk*4;
  #pragma unroll
  for (int mt=0;mt<2;mt++){
    int y = ybase + mt;
    #pragma unroll
    for (int n=0;n<4;n++){
      int ocg = ocb*64 + n*16 + lx;
      if (ocg < Cout){
        float bv = has_bias ? bias[ocg] : 0.f;
        #pragma unroll
        for (int r=0;r<4;r++){
          int xg = xbase + r;
          float v = acc[mt][n][r] + bv;
          if (add_hi){
            long ap = ((long)img*add_ps + y*WW + xg)*add_cs + ocg;
            v += bfu2f(add_hi[ap]) + bfu2f(add_lo[ap]);
          }
          if (relu) v = fmaxf(v, 0.f);
          if (out_pf){
            out_pf[((long)img*pf_C + ocg)*HW + y*WW + xg] = v;
          } else {
            long pp = (long)img*out_ps + y*WW + xg;
            ush h = f2bfu(v);
            out_hi[pp*out_cs + ocg] = h;
            if (out_lo) out_lo[pp*out_cs + ocg] = f2bfu(v - bfu2f(h));
          }
        }
      }
    }
  }
}

// ---------- repack NHWC hi/lo -> group-planar f32 [4][8][HW][8]
__global__ __launch_bounds__(256) void repack_gp(const ush* __restrict__ in_h,
    const ush* __restrict__ in_l, long in_ps, float* __restrict__ gp){
  long idx = (long)blockIdx.x*256 + threadIdx.x;
  int img = (int)(idx >> 20);
  int rem = (int)(idx & 1048575);
  int g = rem >> 17;
  int r2 = rem & 131071;
  int pix = r2 >> 3, c = r2 & 7;
  long src = ((long)img*in_ps + pix)*64 + g*8 + c;
  gp[idx] = bfu2f(in_h[src]) + bfu2f(in_l[src]);
}

// ---------- MFMA modulated deformable conv
__global__ __launch_bounds__(256) void dcn_mfma(
    const float* __restrict__ gp,
    const float* __restrict__ om,
    const ush* __restrict__ wpk,
    const float* __restrict__ bias,
    ush* __restrict__ out_hi, ush* __restrict__ out_lo)
{
  __shared__ ush Ah[128*104];
  __shared__ ush Al[128*104];
  __shared__ ush Bt[64*104];
  int tid = threadIdx.x;
  int gy = blockIdx.x, img = blockIdx.y;
  {
    short8 z = {0,0,0,0,0,0,0,0};
    for (int j=tid; j<384; j+=256){
      int px = j/3, c = j - px*3;
      *(short8*)(Ah + px*104 + 72 + c*8) = z;
      *(short8*)(Al + px*104 + 72 + c*8) = z;
    }
  }
  int w = tid>>6, l = tid&63, lx = l&15, lk = l>>4;
  int px_s = tid & 127, hf = tid >> 7;
  const float* omb = om + (long)img*216*HW + gy*WW + px_s;
  floatx4 acc[2][4];
  #pragma unroll
  for (int mt=0;mt<2;mt++)
    #pragma unroll
    for (int n=0;n<4;n++) acc[mt][n] = (floatx4){0.f,0.f,0.f,0.f};

  #pragma unroll 1
  for (int g=0; g<8; g++){
    __syncthreads();
    const ush* wsrc = wpk + g*6144;
    for (int j=tid; j<768; j+=256){
      int oc = j/12, kc = j - oc*12;
      *(short8*)(Bt + oc*104 + kc*8) = *(const short8*)(wsrc + oc*96 + kc*8);
    }
    const float* gpb = gp + ((long)(img*8+g))*HW*8;
    int t0 = hf ? 5 : 0, t1 = hf ? 9 : 5;
    #pragma unroll 1
    for (int t=t0; t<t1; t++){
      int ch = g*9+t;
      float dy = omb[(long)ch*HW];
      float dx = omb[(long)(72+ch)*HW];
      float mv = omb[(long)(144+ch)*HW];
      float m = 1.f/(1.f+__expf(-mv));
      float py = (float)gy + (float)(t/3 - 1) + dy;
      float pxf = (float)px_s + (float)(t%3 - 1) + dx;
      float fy = floorf(py), fx = floorf(pxf);
      int y0 = (int)fy, x0 = (int)fx;
      float wy = py - fy, wx = pxf - fx;
      bool y0v = (y0>=0 && y0<HH), y1v = (y0+1>=0 && y0+1<HH);
      bool x0v = (x0>=0 && x0<WW), x1v = (x0+1>=0 && x0+1<WW);
      float w00 = (1.f-wy)*(1.f-wx)*m * ((y0v&&x0v)?1.f:0.f);
      float w01 = (1.f-wy)*wx*m      * ((y0v&&x1v)?1.f:0.f);
      float w10 = wy*(1.f-wx)*m      * ((y1v&&x0v)?1.f:0.f);
      float w11 = wy*wx*m            * ((y1v&&x1v)?1.f:0.f);
      int y0c = min(max(y0,0),HH-1), y1c = min(max(y0+1,0),HH-1);
      int x0c = min(max(x0,0),WW-1), x1c = min(max(x0+1,0),WW-1);
      const float* p00 = gpb + ((long)(y0c*WW+x0c)<<3);
      const float* p01 = gpb + ((long)(y0c*WW+x1c)<<3);
      const float* p10 = gpb + ((long)(y1c*WW+x0c)<<3);
      const float* p11 = gpb + ((long)(y1c*WW+x1c)<<3);
      float4 a00=*(const float4*)p00, b00=*(const float4*)(p00+4);
      float4 a01=*(const float4*)p01, b01=*(const float4*)(p01+4);
      float4 a10=*(const float4*)p10, b10=*(const float4*)(p10+4);
      float4 a11=*(const float4*)p11, b11=*(const float4*)(p11+4);
      float val[8];
      val[0]=w00*a00.x+w01*a01.x+w10*a10.x+w11*a11.x;
      val[1]=w00*a00.y+w01*a01.y+w10*a10.y+w11*a11.y;
      val[2]=w00*a00.z+w01*a01.z+w10*a10.z+w11*a11.z;
      val[3]=w00*a00.w+w01*a01.w+w10*a10.w+w11*a11.w;
      val[4]=w00*b00.x+w01*b01.x+w10*b10.x+w11*b11.x;
      val[5]=w00*b00.y+w01*b01.y+w10*b10.y+w11*b11.y;
      val[6]=w00*b00.z+w01*b01.z+w10*b10.z+w11*b11.z;
      val[7]=w00*b00.w+w01*b01.w+w10*b10.w+w11*b11.w;
      short8 vh, vl;
      #pragma unroll
      for (int c=0;c<8;c++){
        ush h = f2bfu(val[c]);
        vh[c] = (short)h;
        vl[c] = (short)f2bfu(val[c] - bfu2f(h));
      }
      *(short8*)(Ah + px_s*104 + t*8) = vh;
      *(short8*)(Al + px_s*104 + t*8) = vl;
    }
    __syncthreads();
    #pragma unroll
    for (int ks=0; ks<3; ks++){
      short8 bfg[4];
      #pragma unroll
      for (int n=0;n<4;n++)
        bfg[n] = *(const short8*)(Bt + (n*16+lx)*104 + ks*32 + lk*8);
      #pragma unroll
      for (int mt=0; mt<2; mt++){
        int px = (w*2+mt)*16 + lx;
        short8 ah = *(const short8*)(Ah + px*104 + ks*32 + lk*8);
        short8 al = *(const short8*)(Al + px*104 + ks*32 + lk*8);
        #pragma unroll
        for (int n=0;n<4;n++){
          acc[mt][n] = __builtin_amdgcn_mfma_f32_16x16x32_bf16(ah, bfg[n], acc[mt][n], 0,0,0);
          acc[mt][n] = __builtin_amdgcn_mfma_f32_16x16x32_bf16(al, bfg[n], acc[mt][n], 0,0,0);
        }
      }
    }
  }
  long base = ((long)img*HW + gy*WW)*64;
  #pragma unroll
  for (int mt=0;mt<2;mt++){
    #pragma unroll
    for (int n=0;n<4;n++){
      int oc = n*16 + lx;
      float bv = bias[oc];
      #pragma unroll
      for (int r=0;r<4;r++){
        int pxl = (w*2+mt)*16 + lk*4 + r;
        float v = acc[mt][n][r] + bv;
        ush h = f2bfu(v);
        out_hi[base + (long)pxl*64 + oc] = h;
        out_lo[base + (long)pxl*64 + oc] = f2bfu(v - bfu2f(h));
      }
    }
  }
}

// ---------- reconstruction conv: fea NHWC hi/lo -> d_out slot ni
__global__ __launch_bounds__(256) void rec_kernel(
    const ush* __restrict__ fh, const ush* __restrict__ fl,
    const float* __restrict__ wT, const float* __restrict__ bias,
    void* __restrict__ out, int ni, const float* __restrict__ flag){
  int tx = threadIdx.x & 15, ty = threadIdx.x >> 4;
  int gx = blockIdx.x*16+tx, gy = blockIdx.y*16+ty;
  int b = blockIdx.z;
  float acc = bias[0];
  #pragma unroll 1
  for (int t=0;t<9;t++){
    int yy = gy + t/3 - 1, xx = gx + t%3 - 1;
    if (yy<0||yy>=HH||xx<0||xx>=WW) continue;
    long base = ((long)b*HW + yy*WW + xx)*64;
    #pragma unroll
    for (int c8=0;c8<8;c8++){
      short8 h = *(const short8*)(fh + base + c8*8);
      short8 lo = *(const short8*)(fl + base + c8*8);
      #pragma unroll
      for (int cc=0;cc<8;cc++){
        float v = bfu2f((ush)h[cc]) + bfu2f((ush)lo[cc]);
        acc = fmaf(v, wT[(c8*8+cc)*9 + t], acc);
      }
    }
  }
  long idx = ((long)b*5+ni)*HW + gy*WW + gx;
  if (flag[0] > 0.5f) ((bf16*)out)[idx] = __float2bfloat16(acc);
  else                ((float*)out)[idx] = acc;
}

extern "C" void kernel_launch(void* const* d_in, const int* in_sizes, int n_in,
                              void* d_out, int out_size, void* d_ws, size_t ws_size,
                              hipStream_t stream) {
  float* ws = (float*)d_ws;

  size_t off = 16;
  auto alloc = [&](size_t nel){ size_t o = off; off += (nel + 7) & ~(size_t)7; return o; };

  static const int IN_N[17] = {327680, 576, 64, 184320, 320, 184320, 320,
                               73728, 64, 147456, 256, 497664, 864, 147456,
                               256, 576, 1};
  size_t cin[17];
  for (int i=0;i<17;i++) cin[i] = alloc(IN_N[i]);

  size_t wt_init = alloc(640);
  size_t wdcn_pk[4]; for (int s=0;s<4;s++) wdcn_pk[s] = alloc(24576);
  size_t wt_rec = alloc(640);
  size_t pk_res1[5], pk_res2[5];
  for (int i=0;i<5;i++) pk_res1[i] = alloc(18432);
  for (int i=0;i<5;i++) pk_res2[i] = alloc(18432);
  size_t pk_bn[2]; for (int h=0;h<2;h++) pk_bn[h] = alloc(18432);
  size_t pk_off[4]; for (int s=0;s<4;s++) pk_off[s] = alloc(18432);
  size_t pk_com[4]; for (int s=0;s<4;s++) pk_com[s] = alloc(73728);

  size_t feat_h_o = alloc(10485760);
  size_t feat_l_o = alloc(10485760);
  size_t U = alloc(26738688);

  ush* feat_h = (ush*)(ws + feat_h_o);
  ush* feat_l = (ush*)(ws + feat_l_o);
  ush* feaA_h = (ush*)(ws + U);
  ush* feaA_l = (ush*)(ws + U + 2097152);
  ush* feaB_h = (ush*)(ws + U + 4194304);
  ush* feaB_l = (ush*)(ws + U + 6291456);
  ush* obuf_h = (ush*)(ws + U + 8388608);
  ush* obuf_l = (ush*)(ws + U + 10485760);
  float* gpbuf = ws + U + 8388608;
  float* ombuf = ws + U + 12582912;
  ush* hbuf_h = (ush*)(ws + U);
  ush* hbuf_l = (ush*)(ws + U + 10485760);
  ush* part_h = obuf_h;
  ush* part_l = obuf_l;

  float* flag = ws;

  detect_dtype<<<dim3(1), dim3(256), 0, stream>>>((const ush*)d_in[0], flag);
  for (int i=0;i<17;i++){
    int n = IN_N[i];
    convert_in<<<dim3((n+255)/256), dim3(256), 0, stream>>>(d_in[i], ws+cin[i], n, flag);
  }
  const float* b_init = ws+cin[2];
  const float* res_b1 = ws+cin[4];
  const float* res_b2 = ws+cin[6];
  const float* b_bn   = ws+cin[8];
  const float* off_b  = ws+cin[10];
  const float* com_b  = ws+cin[12];
  const float* dcn_b  = ws+cin[14];
  const float* b_rec  = ws+cin[16];

  auto tr = [&](size_t src_o, size_t dst_o, int Co, int CiK){
    int total = Co*CiK;
    transpose_w<<<dim3((total+255)/256), dim3(256), 0, stream>>>(ws+src_o, ws+dst_o, Co, CiK);
  };
  tr(cin[1], wt_init, 64, 9);
  tr(cin[15], wt_rec, 1, 576);
  for (int s=0;s<4;s++)
    pack_dcn_w<<<dim3(192), dim3(256), 0, stream>>>(ws+cin[13]+(size_t)s*36864,
                                                    (ush*)(ws+wdcn_pk[s]));

  auto pack = [&](size_t src_o, size_t dst_o, int Cout, int Cin, int kh, int nOcB){
    int total = nOcB*36864;
    pack_w2<<<dim3((total+255)/256), dim3(256), 0, stream>>>(
        ws+src_o, (ush*)(ws+dst_o), Cout, Cin, kh, nOcB);
  };
  for (int i=0;i<5;i++) pack(cin[3]+(size_t)i*36864, pk_res1[i], 64, 64, 0, 1);
  for (int i=0;i<5;i++) pack(cin[5]+(size_t)i*36864, pk_res2[i], 64, 64, 0, 1);
  for (int h=0;h<2;h++) pack(cin[7], pk_bn[h], 64, 128, h, 1);
  for (int s=0;s<4;s++) pack(cin[9]+(size_t)s*36864,  pk_off[s], 64, 64, 0, 1);
  for (int s=0;s<4;s++) pack(cin[11]+(size_t)s*124416, pk_com[s], 216, 64, 0, 4);

  dim3 cblk(256);
  auto conv = [&](const ush* in_h, const ush* in_l, long in_ps, size_t pk,
                  const float* bias, int has_bias,
                  const ush* add_h, const ush* add_l, long add_ps, int add_cs,
                  ush* o_h, ush* o_l, long out_ps, int out_cs,
                  float* o_pf, int pf_C,
                  int Cout, int nOcB, int relu, int N, int nPl){
    if (nPl == 2)
      conv_mfma<2,2><<<dim3(8,16,N*nOcB), cblk, 0, stream>>>(
          in_h, in_l, in_ps, (const ush*)(ws+pk), bias, has_bias,
          add_h, add_l, add_ps, add_cs, o_h, o_l, out_ps, out_cs,
          o_pf, pf_C, Cout, nOcB, relu);
    else
      conv_mfma<1,3><<<dim3(8,16,N*nOcB), cblk, 0, stream>>>(
          in_h, in_l, in_ps, (const ush*)(ws+pk), bias, has_bias,
          add_h, add_l, add_ps, add_cs, o_h, o_l, out_ps, out_cs,
          o_pf, pf_C, Cout, nOcB, relu);
  };

  // ---- feature extraction
  conv_init_kernel<<<dim3(8,8,20), cblk, 0, stream>>>(ws+cin[0], ws+wt_init, b_init,
                                                      feat_h, feat_l);
  for (int i=0;i<5;i++){
    conv(feat_h, feat_l, HW, pk_res1[i], res_b1+(size_t)i*64, 1,
         nullptr, nullptr, 0, 0, hbuf_h, hbuf_l, HW, 64, nullptr, 0, 64, 1, 1, 20, 2);
    conv(hbuf_h, hbuf_l, HW, pk_res2[i], res_b2+(size_t)i*64, 1,
         feat_h, feat_l, HW, 64, feat_h, feat_l, HW, 64, nullptr, 0, 64, 1, 0, 20, 2);
  }
  // ---- per-neighbor alignment
  for (int i=0;i<5;i++){
    conv(feat_h + (size_t)2*HW*64, feat_l + (size_t)2*HW*64, 5L*HW, pk_bn[0], b_bn, 1,
         nullptr, nullptr, 0, 0, part_h, part_l, HW, 64, nullptr, 0, 64, 1, 0, 4, 2);
    conv(feat_h + (size_t)i*HW*64, feat_l + (size_t)i*HW*64, 5L*HW, pk_bn[1], b_bn, 0,
         part_h, part_l, HW, 64, feaA_h, feaA_l, HW, 64, nullptr, 0, 64, 1, 0, 4, 2);
    ush *fa_h = feaA_h, *fa_l = feaA_l, *fb_h = feaB_h, *fb_l = feaB_l;
    for (int s=0;s<4;s++){
      conv(fa_h, fa_l, HW, pk_off[s], off_b+(size_t)s*64, 1,
           nullptr, nullptr, 0, 0, obuf_h, nullptr, HW, 64, nullptr, 0, 64, 1, 0, 4, 2);
      conv(obuf_h, obuf_h, HW, pk_com[s], com_b+(size_t)s*216, 1,
           nullptr, nullptr, 0, 0, nullptr, nullptr, 0, 0, ombuf, 216, 216, 4, 0, 4, 1);
      const ush *xs_h, *xs_l; long xps;
      if (s == 2){ xs_h = feat_h + (size_t)i*HW*64; xs_l = feat_l + (size_t)i*HW*64; xps = 5L*HW; }
      else       { xs_h = fa_h;                     xs_l = fa_l;                     xps = HW; }
      repack_gp<<<dim3(16384), cblk, 0, stream>>>(xs_h, xs_l, xps, gpbuf);
      dcn_mfma<<<dim3(128,4), cblk, 0, stream>>>(gpbuf, ombuf,
          (const ush*)(ws+wdcn_pk[s]), dcn_b+(size_t)s*64, fb_h, fb_l);
      ush* t;
      t = fa_h; fa_h = fb_h; fb_h = t;
      t = fa_l; fa_l = fb_l; fb_l = t;
    }
    rec_kernel<<<dim3(8,8,4), cblk, 0, stream>>>(fa_h, fa_l, ws+wt_rec, b_rec, d_out, i, flag);
  }
}